// Round 9
// baseline (183.088 us; speedup 1.0000x reference)
//
#include <hip/hip_runtime.h>
#include <math.h>

#define TN 4096
#define HN 2048
#define NB 32
#define NCH 9
#define NCODES 512
#define CDIM 64
#define TAU 1e-3f
#define PTS 256          // points per vq block
#define VQT 512          // vq threads per block

typedef _Float16 f16x8 __attribute__((ext_vector_type(8)));
typedef float f32x4 __attribute__((ext_vector_type(4)));

__device__ __forceinline__ float2 cmulf(float2 a, float2 b) {
    return make_float2(a.x * b.x - a.y * b.y, a.x * b.y + a.y * b.x);
}
__device__ __forceinline__ float2 f2add(float2 a, float2 b) {
    return make_float2(a.x + b.x, a.y + b.y);
}
__device__ __forceinline__ float2 f2sub(float2 a, float2 b) {
    return make_float2(a.x - b.x, a.y - b.y);
}
__device__ __forceinline__ float2 f2scale(float2 a, float s) {
    return make_float2(a.x * s, a.y * s);
}

__device__ __forceinline__ unsigned long long packsi(float s, int i) {
    unsigned u = __float_as_uint(s);
    u = (u & 0x80000000u) ? ~u : (u | 0x80000000u);
    return ((unsigned long long)u << 32) | (unsigned)i;
}
__device__ __forceinline__ float unpacks(unsigned long long v) {
    unsigned u = (unsigned)(v >> 32);
    u = (u & 0x80000000u) ? (u & 0x7fffffffu) : ~u;
    return __uint_as_float(u);
}

// Fragment-tile unit index: [entity16-group][plane][s][hi16][l15], 16B units.
// Element k of entity e: k = 32*s + 8*hi16 + elem, e = group*16 + l15.
__device__ __forceinline__ size_t aunit(int pbase, int plane, int s, int hi16, int l15) {
    return ((size_t)(((pbase * 2 + plane) * 2 + s) * 4 + hi16) << 4) + l15;
}

// prep: bid<512 zero phases; bid 512..543: code fragment tiles (f16 hi/lo,
// aunit layout, 128 KB); bid 544: codebook norms.
__global__ __launch_bounds__(256) void prep_kernel(const float* __restrict__ cb,
                                                   float* __restrict__ cn,
                                                   f16x8* __restrict__ ctiles,
                                                   float* __restrict__ ph) {
    const int bid = blockIdx.x;
    const int tid = threadIdx.x;
    if (bid < 512) {
        ph[bid * 256 + tid] = 0.0f;
        return;
    }
    if (bid < 544) {
        const int u = (bid - 512) * 256 + tid;    // 8192 units
        const int l15 = u & 15;
        const int hi16 = (u >> 4) & 3;
        const int s = (u >> 6) & 1;
        const int plane = (u >> 7) & 1;
        const int cbase = u >> 8;
        const int code = cbase * 16 + l15;
        f16x8 out;
        #pragma unroll
        for (int e = 0; e < 8; ++e) {
            float c = cb[code * CDIM + 32 * s + 8 * hi16 + e];
            _Float16 hh = (_Float16)c;
            out[e] = plane ? (_Float16)(c - (float)hh) : hh;
        }
        ctiles[u] = out;
        return;
    }
    for (int k = tid; k < NCODES; k += 256) {
        const float4* c4 = (const float4*)(cb + (size_t)k * CDIM);
        float s = 0.0f;
        #pragma unroll
        for (int q = 0; q < 16; ++q) {
            float4 c = c4[q];
            s = fmaf(c.x, c.x, s);
            s = fmaf(c.y, c.y, s);
            s = fmaf(c.z, c.z, s);
            s = fmaf(c.w, c.w, s);
        }
        cn[k] = s;
    }
}

// Paired-row Hilbert (radix-4 Stockham, validated r3-r7) + r8 micro-opts:
// h-mask/N folded into last fwd stage, sparse inverse stage 0. 144 blocks.
#define HT 512
__global__ __launch_bounds__(HT) void hilbert_phase_kernel(
    const float* __restrict__ x, float* __restrict__ phases) {
    __shared__ float2 bufA[TN];
    __shared__ float2 bufB[TN];
    __shared__ float2 tw[HN];
    const int tid = threadIdx.x;
    const int row1 = 2 * blockIdx.x;
    const int row2 = row1 + 1;
    const int b1 = row1 / NCH;
    const int b2 = row2 / NCH;
    const float* xr1 = x + (size_t)row1 * TN;
    const float* xr2 = x + (size_t)row2 * TN;
    const float inv = 1.0f / (float)TN;

    for (int i = tid; i < HN; i += HT) {
        float ang = -3.14159265358979323846f * ((float)i / (float)HN);
        float s, c;
        sincosf(ang, &s, &c);
        tw[i] = make_float2(c, s);
    }
    for (int i = tid; i < TN; i += HT) {
        bufA[i] = make_float2(xr1[i], xr2[i]);
    }
    __syncthreads();

    float2* src = bufA;
    float2* dst = bufB;
    // ---- forward: 6 radix-4 DIF Stockham stages; h-mask/N folded in last ----
    for (int stage = 0; stage < 6; ++stage) {
        const int m = 1 << (2 * stage);
        for (int idx = tid; idx < 1024; idx += HT) {
            const int kk = idx & (m - 1);
            const int jm = idx - kk;
            float2 a0 = src[idx];
            float2 a1 = src[idx + 1024];
            float2 a2 = src[idx + 2048];
            float2 a3 = src[idx + 3072];
            float2 b0 = f2add(a0, a2);
            float2 b1 = f2add(a1, a3);
            float2 b2 = f2sub(a0, a2);
            float2 b3 = f2sub(a1, a3);
            float2 y0 = f2add(b0, b1);
            float2 mi = make_float2(b2.x + b3.y, b2.y - b3.x);  // b2 - i*b3
            float2 pi_ = make_float2(b2.x - b3.y, b2.y + b3.x); // b2 + i*b3
            if (stage == 5) {
                const float sA_ = (idx == 0) ? inv : 2.0f * inv;
                const float sC_ = (idx == 0) ? inv : 0.0f;
                dst[idx]        = f2scale(y0, sA_);
                dst[idx + 1024] = f2scale(mi, 2.0f * inv);
                dst[idx + 2048] = f2scale(f2sub(b0, b1), sC_);
                dst[idx + 3072] = make_float2(0.0f, 0.0f);
            } else {
                float2 w1 = tw[jm];
                float2 w2 = tw[2 * jm];
                float2 w3 = cmulf(w1, w2);
                dst[4 * jm + kk]         = y0;
                dst[4 * jm + kk + m]     = cmulf(mi, w1);
                dst[4 * jm + kk + 2 * m] = cmulf(f2sub(b0, b1), w2);
                dst[4 * jm + kk + 3 * m] = cmulf(pi_, w3);
            }
        }
        __syncthreads();
        float2* t0 = src; src = dst; dst = t0;
    }
    // ---- inverse: stage 0 exploits zeroed upper half ----
    for (int stage = 0; stage < 6; ++stage) {
        const int m = 1 << (2 * stage);
        for (int idx = tid; idx < 1024; idx += HT) {
            const int kk = idx & (m - 1);
            const int jm = idx - kk;
            float2 a0 = src[idx];
            float2 a1 = src[idx + 1024];
            float2 a2, a3;
            if (stage == 0) {
                a2 = (idx == 0) ? src[2048] : make_float2(0.0f, 0.0f);
                a3 = make_float2(0.0f, 0.0f);
            } else {
                a2 = src[idx + 2048];
                a3 = src[idx + 3072];
            }
            float2 b0 = f2add(a0, a2);
            float2 b1 = f2add(a1, a3);
            float2 b2 = f2sub(a0, a2);
            float2 b3 = f2sub(a1, a3);
            float2 w1 = tw[jm];      w1.y = -w1.y;
            float2 w2 = tw[2 * jm];  w2.y = -w2.y;
            float2 w3 = cmulf(w1, w2);
            float2 y0 = f2add(b0, b1);
            float2 pi_ = make_float2(b2.x - b3.y, b2.y + b3.x); // b2 + i*b3
            float2 mi = make_float2(b2.x + b3.y, b2.y - b3.x);  // b2 - i*b3
            dst[4 * jm + kk]         = y0;
            dst[4 * jm + kk + m]     = cmulf(pi_, w1);
            dst[4 * jm + kk + 2 * m] = cmulf(f2sub(b0, b1), w2);
            dst[4 * jm + kk + 3 * m] = cmulf(mi, w3);
        }
        __syncthreads();
        float2* t0 = src; src = dst; dst = t0;
    }
    float* ph1 = phases + (size_t)b1 * TN;
    float* ph2 = phases + (size_t)b2 * TN;
    for (int i = tid; i < TN; i += HT) {
        float2 d = src[i];
        float x1v = xr1[i];
        float x2v = xr2[i];
        atomicAdd(&ph1[i], atan2f(d.y - x2v, x1v) * (1.0f / 9.0f));
        atomicAdd(&ph2[i], atan2f(x1v - d.x, x2v) * (1.0f / 9.0f));
    }
}

// feat: 512 blocks x 256 thr, 1 point/thread, 8-dim groups (no spill),
// writes f16 hi/lo point fragment tiles (aunit layout) into out_q region.
__global__ __launch_bounds__(256) void feat_kernel(
    const float* __restrict__ imu,
    const float* __restrict__ Wm, const float* __restrict__ bm,
    const float* __restrict__ Wp, const float* __restrict__ bp,
    const float* __restrict__ phases,
    f16x8* __restrict__ atiles) {
    const int p = blockIdx.x * 256 + threadIdx.x;
    const int bb = p >> 12;
    const int tt = p & (TN - 1);
    float xc[9];
    #pragma unroll
    for (int c = 0; c < 9; ++c)
        xc[c] = imu[((size_t)(bb * 9 + c)) * TN + tt];
    float sp, cp;
    sincosf(phases[p], &sp, &cp);

    const int pbase = p >> 4;
    const int l15 = p & 15;
    #pragma unroll
    for (int g = 0; g < 8; ++g) {
        float v8[8];
        if (g < 4) {
            #pragma unroll
            for (int e = 0; e < 8; ++e) {
                const int j = 8 * g + e;
                float a = bm[j];
                #pragma unroll
                for (int c = 0; c < 9; ++c) a = fmaf(Wm[j * 9 + c], xc[c], a);
                v8[e] = a;
            }
        } else {
            #pragma unroll
            for (int e = 0; e < 8; ++e) {
                const int j = 8 * (g - 4) + e;
                float a = bp[j];
                #pragma unroll
                for (int c = 0; c < 7; ++c) a = fmaf(Wp[j * 9 + c], xc[c], a);
                a = fmaf(Wp[j * 9 + 7], cp, a);
                a = fmaf(Wp[j * 9 + 8], sp, a);
                v8[e] = a;
            }
        }
        f16x8 hv, lv;
        #pragma unroll
        for (int e = 0; e < 8; ++e) {
            _Float16 hh = (_Float16)v8[e];
            hv[e] = hh;
            lv[e] = (_Float16)(v8[e] - (float)hh);
        }
        const int s = g >> 2;
        const int hi16 = g & 3;
        atiles[aunit(pbase, 0, s, hi16, l15)] = hv;
        atiles[aunit(pbase, 1, s, hi16, l15)] = lv;
    }
}

// vq: 512 blocks x 512 thr (8 waves), 256 pts/block. Codes in REGISTERS
// (wave owns 64 codes as 2 halves of 32), points stream from atiles (L2)
// as B-fragments. NO k-loop barriers. Per-(wave,half,cf) top-2 -> LDS;
// block merge; rare exact f32 rescan; gather epilogue.
__global__ __launch_bounds__(VQT, 4) void vq_kernel(
    const float* __restrict__ imu,
    const float* __restrict__ Wm, const float* __restrict__ bm,
    const float* __restrict__ Wp, const float* __restrict__ bp,
    const float* __restrict__ cb,
    const float* __restrict__ cn,
    const f16x8* __restrict__ ctiles,
    const float* __restrict__ phases,
    const f16x8* atiles,           // aliases out_q (no __restrict__)
    float* out_q,
    float* __restrict__ out_i) {
    __shared__ unsigned long long s_bs[16][PTS][2];   // 64 KB
    __shared__ int s_idx[PTS];
    __shared__ float s_gap[PTS];
    const int tid = threadIdx.x;
    const int lane = tid & 63;
    const int w = tid >> 6;          // 8 waves
    const int l15 = lane & 15;
    const int hi16 = lane >> 4;
    const int p0 = blockIdx.x * PTS;
    const int pb0 = p0 >> 4;

    for (int h = 0; h < 2; ++h) {
        const int kbase = 64 * w + 32 * h;      // this pass: codes [kbase, kbase+32)
        f16x8 cH[2][2], cL[2][2];               // [rf][s] code A-fragments
        #pragma unroll
        for (int rf = 0; rf < 2; ++rf) {
            const int cbase = (kbase >> 4) + rf;
            #pragma unroll
            for (int s = 0; s < 2; ++s) {
                cH[rf][s] = ctiles[aunit(cbase, 0, s, hi16, l15)];
                cL[rf][s] = ctiles[aunit(cbase, 1, s, hi16, l15)];
            }
        }
        float cnv[2][4];
        #pragma unroll
        for (int rf = 0; rf < 2; ++rf)
            #pragma unroll
            for (int r = 0; r < 4; ++r)
                cnv[rf][r] = cn[kbase + 16 * rf + 4 * hi16 + r];

        #pragma unroll 4
        for (int cf = 0; cf < 16; ++cf) {
            const int pbase = pb0 + cf;
            f16x8 bH[2], bL[2];
            #pragma unroll
            for (int s = 0; s < 2; ++s) {
                bH[s] = atiles[aunit(pbase, 0, s, hi16, l15)];
                bL[s] = atiles[aunit(pbase, 1, s, hi16, l15)];
            }
            f32x4 acc[2];
            acc[0] = (f32x4){0.f, 0.f, 0.f, 0.f};
            acc[1] = (f32x4){0.f, 0.f, 0.f, 0.f};
            #pragma unroll
            for (int s = 0; s < 2; ++s)
                #pragma unroll
                for (int rf = 0; rf < 2; ++rf) {
                    acc[rf] = __builtin_amdgcn_mfma_f32_16x16x32_f16(cH[rf][s], bH[s], acc[rf], 0, 0, 0);
                    acc[rf] = __builtin_amdgcn_mfma_f32_16x16x32_f16(cH[rf][s], bL[s], acc[rf], 0, 0, 0);
                    acc[rf] = __builtin_amdgcn_mfma_f32_16x16x32_f16(cL[rf][s], bH[s], acc[rf], 0, 0, 0);
                }
            // C layout: row (code) = 16rf+4hi16+r, col (point) = 16cf+l15.
            unsigned long long b = ~0ull, sec = ~0ull;
            #pragma unroll
            for (int rf = 0; rf < 2; ++rf)
                #pragma unroll
                for (int r = 0; r < 4; ++r) {
                    float sc = fmaf(-2.0f, acc[rf][r], cnv[rf][r]);
                    unsigned long long pk = packsi(sc, kbase + 16 * rf + 4 * hi16 + r);
                    unsigned long long mx = b > pk ? b : pk;
                    sec = sec < mx ? sec : mx;
                    b = b < pk ? b : pk;
                }
            #pragma unroll
            for (int m = 16; m <= 32; m <<= 1) {
                unsigned long long ob = __shfl_xor(b, m, 64);
                unsigned long long os = __shfl_xor(sec, m, 64);
                unsigned long long mx = b > ob ? b : ob;
                unsigned long long mn = sec < os ? sec : os;
                sec = mx < mn ? mx : mn;
                b = b < ob ? b : ob;
            }
            if (hi16 == 0) {
                s_bs[2 * w + h][16 * cf + l15][0] = b;
                s_bs[2 * w + h][16 * cf + l15][1] = sec;
            }
        }
    }
    __syncthreads();

    // ---- block merge: 16 partials per point ----
    if (tid < PTS) {
        unsigned long long b = ~0ull, sec = ~0ull;
        #pragma unroll 4
        for (int q = 0; q < 16; ++q) {
            unsigned long long ob = s_bs[q][tid][0];
            unsigned long long os = s_bs[q][tid][1];
            unsigned long long mx = b > ob ? b : ob;
            unsigned long long mn = sec < os ? sec : os;
            sec = mx < mn ? mx : mn;
            b = b < ob ? b : ob;
        }
        const int bi = (int)(b & 0xFFFFFFFFu);
        s_idx[tid] = bi;
        out_i[p0 + tid] = (float)bi;
        s_gap[tid] = unpacks(sec) - unpacks(b);
    }
    __syncthreads();

    // ---- rare exact f32 rescan (streaming feature recompute) ----
    {
        bool fl = (lane < 32) && (s_gap[32 * w + (lane & 31)] < TAU);
        unsigned long long bal = __ballot(fl);
        while (bal) {
            const int ln = __builtin_ctzll(bal);
            bal &= bal - 1;
            const int row = 32 * w + ln;
            const int pR = p0 + row;
            const int bbR = pR >> 12;
            const int ttR = pR & (TN - 1);
            float xcR[9];
            #pragma unroll
            for (int c = 0; c < 9; ++c)
                xcR[c] = imu[((size_t)(bbR * 9 + c)) * TN + ttR];
            float spR, cpR;
            sincosf(phases[pR], &spR, &cpR);
            float a0[8], a1[8], a2[8], a3[8];
            #pragma unroll
            for (int cc = 0; cc < 8; ++cc) {
                a0[cc] = 0.f; a1[cc] = 0.f; a2[cc] = 0.f; a3[cc] = 0.f;
            }
            for (int d4 = 0; d4 < 16; ++d4) {
                float fd[4];
                #pragma unroll
                for (int e = 0; e < 4; ++e) {
                    const int j = 4 * d4 + e;
                    float a;
                    if (j < 32) {
                        a = bm[j];
                        #pragma unroll
                        for (int c = 0; c < 9; ++c) a = fmaf(Wm[j * 9 + c], xcR[c], a);
                    } else {
                        const int jj = j - 32;
                        a = bp[jj];
                        #pragma unroll
                        for (int c = 0; c < 7; ++c) a = fmaf(Wp[jj * 9 + c], xcR[c], a);
                        a = fmaf(Wp[jj * 9 + 7], cpR, a);
                        a = fmaf(Wp[jj * 9 + 8], spR, a);
                    }
                    fd[e] = a;
                }
                #pragma unroll
                for (int cc = 0; cc < 8; ++cc) {
                    const float4 cv = ((const float4*)(cb + (size_t)(lane * 8 + cc) * CDIM))[d4];
                    a0[cc] = fmaf(fd[0], cv.x, a0[cc]);
                    a1[cc] = fmaf(fd[1], cv.y, a1[cc]);
                    a2[cc] = fmaf(fd[2], cv.z, a2[cc]);
                    a3[cc] = fmaf(fd[3], cv.w, a3[cc]);
                }
            }
            unsigned long long pbest = ~0ull;
            #pragma unroll
            for (int cc = 0; cc < 8; ++cc) {
                const int kk = lane * 8 + cc;
                float sc = fmaf(-2.0f, (a0[cc] + a1[cc]) + (a2[cc] + a3[cc]), cn[kk]);
                unsigned long long pk = packsi(sc, kk);
                pbest = pk < pbest ? pk : pbest;
            }
            #pragma unroll
            for (int m = 1; m <= 32; m <<= 1) {
                unsigned long long o = __shfl_xor(pbest, m, 64);
                pbest = o < pbest ? o : pbest;
            }
            if (lane == 0) {
                const int bi = (int)(pbest & 0xFFFFFFFFu);
                s_idx[row] = bi;
                out_i[p0 + row] = (float)bi;
            }
        }
    }
    __syncthreads();

    // ---- cooperative coalesced gather of quantized rows (L2-hot cb) ----
    float4* oq = (float4*)out_q;
    const float4* c4g = (const float4*)cb;
    for (int i = tid; i < PTS * 16; i += VQT) {
        const int pt = i >> 4;
        const int q = i & 15;
        oq[(size_t)(p0 + pt) * 16 + q] = c4g[(size_t)s_idx[pt] * 16 + q];
    }
}

extern "C" void kernel_launch(void* const* d_in, const int* in_sizes, int n_in,
                              void* d_out, int out_size, void* d_ws, size_t ws_size,
                              hipStream_t stream) {
    const float* imu = (const float*)d_in[0];
    const float* Wm  = (const float*)d_in[1];
    const float* bm  = (const float*)d_in[2];
    const float* Wp  = (const float*)d_in[3];
    const float* bp  = (const float*)d_in[4];
    const float* cb  = (const float*)d_in[5];

    float* out_q = (float*)d_out;                          // (32,4096,64)
    float* out_i = out_q + (size_t)NB * TN * CDIM;         // (32,4096) as float
    float* out_p = out_i + (size_t)NB * TN;                // (32,4096) phases

    float* cn     = (float*)d_ws;                          // 512 f32
    f16x8* ctiles = (f16x8*)((char*)d_ws + 2048);          // 128 KB code tiles
    f16x8* atiles = (f16x8*)out_q;                         // point tiles in out_q

    prep_kernel<<<545, 256, 0, stream>>>(cb, cn, ctiles, out_p);
    hilbert_phase_kernel<<<NB * NCH / 2, HT, 0, stream>>>(imu, out_p);
    feat_kernel<<<(NB * TN) / 256, 256, 0, stream>>>(imu, Wm, bm, Wp, bp, out_p, atiles);
    vq_kernel<<<(NB * TN) / PTS, VQT, 0, stream>>>(imu, Wm, bm, Wp, bp, cb,
                                                   cn, ctiles, out_p, atiles,
                                                   out_q, out_i);
}

// Round 10
// 180.772 us; speedup vs baseline: 1.0128x; 1.0128x over previous
//
#include <hip/hip_runtime.h>
#include <math.h>

#define TN 4096
#define HN 2048
#define NB 32
#define NCH 9
#define NCODES 512
#define CDIM 64
#define TAU 1e-3f
#define PTS 256          // points per vq block
#define VQT 512          // vq threads per block

typedef _Float16 f16x8 __attribute__((ext_vector_type(8)));
typedef float f32x4 __attribute__((ext_vector_type(4)));

__device__ __forceinline__ float2 cmulf(float2 a, float2 b) {
    return make_float2(a.x * b.x - a.y * b.y, a.x * b.y + a.y * b.x);
}
__device__ __forceinline__ float2 f2add(float2 a, float2 b) {
    return make_float2(a.x + b.x, a.y + b.y);
}
__device__ __forceinline__ float2 f2sub(float2 a, float2 b) {
    return make_float2(a.x - b.x, a.y - b.y);
}

__device__ __forceinline__ unsigned long long packsi(float s, int i) {
    unsigned u = __float_as_uint(s);
    u = (u & 0x80000000u) ? ~u : (u | 0x80000000u);
    return ((unsigned long long)u << 32) | (unsigned)i;
}
__device__ __forceinline__ float unpacks(unsigned long long v) {
    unsigned u = (unsigned)(v >> 32);
    u = (u & 0x80000000u) ? (u & 0x7fffffffu) : ~u;
    return __uint_as_float(u);
}

// Fragment-tile unit index: [entity16-group][plane][s][hi16][l15], 16B units.
__device__ __forceinline__ size_t aunit(int pbase, int plane, int s, int hi16, int l15) {
    return ((size_t)(((pbase * 2 + plane) * 2 + s) * 4 + hi16) << 4) + l15;
}

// prep: bid<512 zero phases; bid 512..543: code fragment tiles; bid 544: norms.
__global__ __launch_bounds__(256) void prep_kernel(const float* __restrict__ cb,
                                                   float* __restrict__ cn,
                                                   f16x8* __restrict__ ctiles,
                                                   float* __restrict__ ph) {
    const int bid = blockIdx.x;
    const int tid = threadIdx.x;
    if (bid < 512) {
        ph[bid * 256 + tid] = 0.0f;
        return;
    }
    if (bid < 544) {
        const int u = (bid - 512) * 256 + tid;    // 8192 units
        const int l15 = u & 15;
        const int hi16 = (u >> 4) & 3;
        const int s = (u >> 6) & 1;
        const int plane = (u >> 7) & 1;
        const int cbase = u >> 8;
        const int code = cbase * 16 + l15;
        f16x8 out;
        #pragma unroll
        for (int e = 0; e < 8; ++e) {
            float c = cb[code * CDIM + 32 * s + 8 * hi16 + e];
            _Float16 hh = (_Float16)c;
            out[e] = plane ? (_Float16)(c - (float)hh) : hh;
        }
        ctiles[u] = out;
        return;
    }
    for (int k = tid; k < NCODES; k += 256) {
        const float4* c4 = (const float4*)(cb + (size_t)k * CDIM);
        float s = 0.0f;
        #pragma unroll
        for (int q = 0; q < 16; ++q) {
            float4 c = c4[q];
            s = fmaf(c.x, c.x, s);
            s = fmaf(c.y, c.y, s);
            s = fmaf(c.z, c.z, s);
            s = fmaf(c.w, c.w, s);
        }
        cn[k] = s;
    }
}

// Paired-row Hilbert (radix-4 Stockham) — exact r7 form (best measured).
#define HT 512
__global__ __launch_bounds__(HT) void hilbert_phase_kernel(
    const float* __restrict__ x, float* __restrict__ phases) {
    __shared__ float2 bufA[TN];
    __shared__ float2 bufB[TN];
    __shared__ float2 tw[HN];
    const int tid = threadIdx.x;
    const int row1 = 2 * blockIdx.x;
    const int row2 = row1 + 1;
    const int b1 = row1 / NCH;
    const int b2 = row2 / NCH;
    const float* xr1 = x + (size_t)row1 * TN;
    const float* xr2 = x + (size_t)row2 * TN;

    for (int i = tid; i < HN; i += HT) {
        float ang = -3.14159265358979323846f * ((float)i / (float)HN);
        float s, c;
        sincosf(ang, &s, &c);
        tw[i] = make_float2(c, s);
    }
    for (int i = tid; i < TN; i += HT) {
        bufA[i] = make_float2(xr1[i], xr2[i]);
    }
    __syncthreads();

    float2* src = bufA;
    float2* dst = bufB;
    for (int stage = 0; stage < 6; ++stage) {
        const int m = 1 << (2 * stage);
        for (int idx = tid; idx < 1024; idx += HT) {
            const int kk = idx & (m - 1);
            const int jm = idx - kk;
            float2 a0 = src[idx];
            float2 a1 = src[idx + 1024];
            float2 a2 = src[idx + 2048];
            float2 a3 = src[idx + 3072];
            float2 b0 = f2add(a0, a2);
            float2 b1 = f2add(a1, a3);
            float2 b2 = f2sub(a0, a2);
            float2 b3 = f2sub(a1, a3);
            float2 w1 = tw[jm];
            float2 w2 = tw[2 * jm];
            float2 w3 = cmulf(w1, w2);
            float2 y0 = f2add(b0, b1);
            float2 mi = make_float2(b2.x + b3.y, b2.y - b3.x);
            float2 pi_ = make_float2(b2.x - b3.y, b2.y + b3.x);
            dst[4 * jm + kk]         = y0;
            dst[4 * jm + kk + m]     = cmulf(mi, w1);
            dst[4 * jm + kk + 2 * m] = cmulf(f2sub(b0, b1), w2);
            dst[4 * jm + kk + 3 * m] = cmulf(pi_, w3);
        }
        __syncthreads();
        float2* t0 = src; src = dst; dst = t0;
    }
    const float inv = 1.0f / (float)TN;
    for (int i = tid; i < TN; i += HT) {
        float sc;
        if (i == 0 || i == HN) sc = inv;
        else if (i < HN) sc = 2.0f * inv;
        else sc = 0.0f;
        float2 v = src[i];
        v.x *= sc; v.y *= sc;
        src[i] = v;
    }
    __syncthreads();
    for (int stage = 0; stage < 6; ++stage) {
        const int m = 1 << (2 * stage);
        for (int idx = tid; idx < 1024; idx += HT) {
            const int kk = idx & (m - 1);
            const int jm = idx - kk;
            float2 a0 = src[idx];
            float2 a1 = src[idx + 1024];
            float2 a2 = src[idx + 2048];
            float2 a3 = src[idx + 3072];
            float2 b0 = f2add(a0, a2);
            float2 b1 = f2add(a1, a3);
            float2 b2 = f2sub(a0, a2);
            float2 b3 = f2sub(a1, a3);
            float2 w1 = tw[jm];      w1.y = -w1.y;
            float2 w2 = tw[2 * jm];  w2.y = -w2.y;
            float2 w3 = cmulf(w1, w2);
            float2 y0 = f2add(b0, b1);
            float2 pi_ = make_float2(b2.x - b3.y, b2.y + b3.x);
            float2 mi = make_float2(b2.x + b3.y, b2.y - b3.x);
            dst[4 * jm + kk]         = y0;
            dst[4 * jm + kk + m]     = cmulf(pi_, w1);
            dst[4 * jm + kk + 2 * m] = cmulf(f2sub(b0, b1), w2);
            dst[4 * jm + kk + 3 * m] = cmulf(mi, w3);
        }
        __syncthreads();
        float2* t0 = src; src = dst; dst = t0;
    }
    float* ph1 = phases + (size_t)b1 * TN;
    float* ph2 = phases + (size_t)b2 * TN;
    for (int i = tid; i < TN; i += HT) {
        float2 d = src[i];
        float x1v = xr1[i];
        float x2v = xr2[i];
        atomicAdd(&ph1[i], atan2f(d.y - x2v, x1v) * (1.0f / 9.0f));
        atomicAdd(&ph2[i], atan2f(x1v - d.x, x2v) * (1.0f / 9.0f));
    }
}

// feat: writes f16 hi/lo point fragment tiles (aunit layout) into out_q region.
__global__ __launch_bounds__(256) void feat_kernel(
    const float* __restrict__ imu,
    const float* __restrict__ Wm, const float* __restrict__ bm,
    const float* __restrict__ Wp, const float* __restrict__ bp,
    const float* __restrict__ phases,
    f16x8* __restrict__ atiles) {
    const int p = blockIdx.x * 256 + threadIdx.x;
    const int bb = p >> 12;
    const int tt = p & (TN - 1);
    float xc[9];
    #pragma unroll
    for (int c = 0; c < 9; ++c)
        xc[c] = imu[((size_t)(bb * 9 + c)) * TN + tt];
    float sp, cp;
    sincosf(phases[p], &sp, &cp);

    const int pbase = p >> 4;
    const int l15 = p & 15;
    #pragma unroll
    for (int g = 0; g < 8; ++g) {
        float v8[8];
        if (g < 4) {
            #pragma unroll
            for (int e = 0; e < 8; ++e) {
                const int j = 8 * g + e;
                float a = bm[j];
                #pragma unroll
                for (int c = 0; c < 9; ++c) a = fmaf(Wm[j * 9 + c], xc[c], a);
                v8[e] = a;
            }
        } else {
            #pragma unroll
            for (int e = 0; e < 8; ++e) {
                const int j = 8 * (g - 4) + e;
                float a = bp[j];
                #pragma unroll
                for (int c = 0; c < 7; ++c) a = fmaf(Wp[j * 9 + c], xc[c], a);
                a = fmaf(Wp[j * 9 + 7], cp, a);
                a = fmaf(Wp[j * 9 + 8], sp, a);
                v8[e] = a;
            }
        }
        f16x8 hv, lv;
        #pragma unroll
        for (int e = 0; e < 8; ++e) {
            _Float16 hh = (_Float16)v8[e];
            hv[e] = hh;
            lv[e] = (_Float16)(v8[e] - (float)hh);
        }
        const int s = g >> 2;
        const int hi16 = g & 3;
        atiles[aunit(pbase, 0, s, hi16, l15)] = hv;
        atiles[aunit(pbase, 1, s, hi16, l15)] = lv;
    }
}

#define MFMA16(A, B, C) __builtin_amdgcn_mfma_f32_16x16x32_f16((A), (B), (C), 0, 0, 0)

// vq: 512 blocks x 512 thr (8 waves), 256 pts/block. Codes in registers,
// PINNED via asm so the compiler cannot rematerialize the global loads
// (r9 failure: VGPR=60 proved frags were reloaded every cf). Points stream
// from atiles; no k-loop barriers; in-block merge + rescan + gather.
__global__ __launch_bounds__(VQT, 4) void vq_kernel(
    const float* __restrict__ imu,
    const float* __restrict__ Wm, const float* __restrict__ bm,
    const float* __restrict__ Wp, const float* __restrict__ bp,
    const float* __restrict__ cb,
    const float* __restrict__ cn,
    const f16x8* __restrict__ ctiles,
    const float* __restrict__ phases,
    const f16x8* atiles,           // aliases out_q (no __restrict__)
    float* out_q,
    float* __restrict__ out_i) {
    __shared__ unsigned long long s_bs[16][PTS][2];   // 64 KB
    __shared__ int s_idx[PTS];
    __shared__ float s_gap[PTS];
    const int tid = threadIdx.x;
    const int lane = tid & 63;
    const int w = tid >> 6;          // 8 waves
    const int l15 = lane & 15;
    const int hi16 = lane >> 4;
    const int p0 = blockIdx.x * PTS;
    const int pb0 = p0 >> 4;

    for (int h = 0; h < 2; ++h) {
        const int kbase = 64 * w + 32 * h;      // codes [kbase, kbase+32)
        const int cb0 = kbase >> 4;
        // ---- code fragments, loaded once and PINNED in VGPRs ----
        f16x8 cH00 = ctiles[aunit(cb0 + 0, 0, 0, hi16, l15)];
        f16x8 cH01 = ctiles[aunit(cb0 + 0, 0, 1, hi16, l15)];
        f16x8 cH10 = ctiles[aunit(cb0 + 1, 0, 0, hi16, l15)];
        f16x8 cH11 = ctiles[aunit(cb0 + 1, 0, 1, hi16, l15)];
        f16x8 cL00 = ctiles[aunit(cb0 + 0, 1, 0, hi16, l15)];
        f16x8 cL01 = ctiles[aunit(cb0 + 0, 1, 1, hi16, l15)];
        f16x8 cL10 = ctiles[aunit(cb0 + 1, 1, 0, hi16, l15)];
        f16x8 cL11 = ctiles[aunit(cb0 + 1, 1, 1, hi16, l15)];
        f32x4 cnv0 = ((const f32x4*)(cn + kbase))[hi16 & 0];  // placeholder shape
        cnv0 = *(const f32x4*)(cn + kbase + 4 * hi16);
        f32x4 cnv1 = *(const f32x4*)(cn + kbase + 16 + 4 * hi16);
        asm volatile("" : "+v"(cH00), "+v"(cH01), "+v"(cH10), "+v"(cH11),
                          "+v"(cL00), "+v"(cL01), "+v"(cL10), "+v"(cL11));
        asm volatile("" : "+v"(cnv0), "+v"(cnv1));

        #pragma unroll 2
        for (int cf = 0; cf < 16; ++cf) {
            const int pbase = pb0 + cf;
            f16x8 bH0 = atiles[aunit(pbase, 0, 0, hi16, l15)];
            f16x8 bH1 = atiles[aunit(pbase, 0, 1, hi16, l15)];
            f16x8 bL0 = atiles[aunit(pbase, 1, 0, hi16, l15)];
            f16x8 bL1 = atiles[aunit(pbase, 1, 1, hi16, l15)];
            f32x4 a0 = (f32x4){0.f, 0.f, 0.f, 0.f};
            f32x4 a1 = (f32x4){0.f, 0.f, 0.f, 0.f};
            a0 = MFMA16(cH00, bH0, a0);
            a0 = MFMA16(cH00, bL0, a0);
            a0 = MFMA16(cL00, bH0, a0);
            a0 = MFMA16(cH01, bH1, a0);
            a0 = MFMA16(cH01, bL1, a0);
            a0 = MFMA16(cL01, bH1, a0);
            a1 = MFMA16(cH10, bH0, a1);
            a1 = MFMA16(cH10, bL0, a1);
            a1 = MFMA16(cL10, bH0, a1);
            a1 = MFMA16(cH11, bH1, a1);
            a1 = MFMA16(cH11, bL1, a1);
            a1 = MFMA16(cL11, bH1, a1);
            // C layout: row (code) = 16rf+4hi16+r, col (point) = 16cf+l15
            unsigned long long b = ~0ull, sec = ~0ull;
            #pragma unroll
            for (int r = 0; r < 4; ++r) {
                float sc = fmaf(-2.0f, a0[r], cnv0[r]);
                unsigned long long pk = packsi(sc, kbase + 4 * hi16 + r);
                unsigned long long mx = b > pk ? b : pk;
                sec = sec < mx ? sec : mx;
                b = b < pk ? b : pk;
            }
            #pragma unroll
            for (int r = 0; r < 4; ++r) {
                float sc = fmaf(-2.0f, a1[r], cnv1[r]);
                unsigned long long pk = packsi(sc, kbase + 16 + 4 * hi16 + r);
                unsigned long long mx = b > pk ? b : pk;
                sec = sec < mx ? sec : mx;
                b = b < pk ? b : pk;
            }
            #pragma unroll
            for (int m = 16; m <= 32; m <<= 1) {
                unsigned long long ob = __shfl_xor(b, m, 64);
                unsigned long long os = __shfl_xor(sec, m, 64);
                unsigned long long mx = b > ob ? b : ob;
                unsigned long long mn = sec < os ? sec : os;
                sec = mx < mn ? mx : mn;
                b = b < ob ? b : ob;
            }
            if (hi16 == 0) {
                s_bs[2 * w + h][16 * cf + l15][0] = b;
                s_bs[2 * w + h][16 * cf + l15][1] = sec;
            }
        }
    }
    __syncthreads();

    // ---- block merge: 16 partials per point ----
    if (tid < PTS) {
        unsigned long long b = ~0ull, sec = ~0ull;
        #pragma unroll 4
        for (int q = 0; q < 16; ++q) {
            unsigned long long ob = s_bs[q][tid][0];
            unsigned long long os = s_bs[q][tid][1];
            unsigned long long mx = b > ob ? b : ob;
            unsigned long long mn = sec < os ? sec : os;
            sec = mx < mn ? mx : mn;
            b = b < ob ? b : ob;
        }
        const int bi = (int)(b & 0xFFFFFFFFu);
        s_idx[tid] = bi;
        out_i[p0 + tid] = (float)bi;
        s_gap[tid] = unpacks(sec) - unpacks(b);
    }
    __syncthreads();

    // ---- rare exact f32 rescan (streaming feature recompute) ----
    {
        bool fl = (lane < 32) && (s_gap[32 * w + (lane & 31)] < TAU);
        unsigned long long bal = __ballot(fl);
        while (bal) {
            const int ln = __builtin_ctzll(bal);
            bal &= bal - 1;
            const int row = 32 * w + ln;
            const int pR = p0 + row;
            const int bbR = pR >> 12;
            const int ttR = pR & (TN - 1);
            float xcR[9];
            #pragma unroll
            for (int c = 0; c < 9; ++c)
                xcR[c] = imu[((size_t)(bbR * 9 + c)) * TN + ttR];
            float spR, cpR;
            sincosf(phases[pR], &spR, &cpR);
            float a0[8], a1[8], a2[8], a3[8];
            #pragma unroll
            for (int cc = 0; cc < 8; ++cc) {
                a0[cc] = 0.f; a1[cc] = 0.f; a2[cc] = 0.f; a3[cc] = 0.f;
            }
            for (int d4 = 0; d4 < 16; ++d4) {
                float fd[4];
                #pragma unroll
                for (int e = 0; e < 4; ++e) {
                    const int j = 4 * d4 + e;
                    float a;
                    if (j < 32) {
                        a = bm[j];
                        #pragma unroll
                        for (int c = 0; c < 9; ++c) a = fmaf(Wm[j * 9 + c], xcR[c], a);
                    } else {
                        const int jj = j - 32;
                        a = bp[jj];
                        #pragma unroll
                        for (int c = 0; c < 7; ++c) a = fmaf(Wp[jj * 9 + c], xcR[c], a);
                        a = fmaf(Wp[jj * 9 + 7], cpR, a);
                        a = fmaf(Wp[jj * 9 + 8], spR, a);
                    }
                    fd[e] = a;
                }
                #pragma unroll
                for (int cc = 0; cc < 8; ++cc) {
                    const float4 cv = ((const float4*)(cb + (size_t)(lane * 8 + cc) * CDIM))[d4];
                    a0[cc] = fmaf(fd[0], cv.x, a0[cc]);
                    a1[cc] = fmaf(fd[1], cv.y, a1[cc]);
                    a2[cc] = fmaf(fd[2], cv.z, a2[cc]);
                    a3[cc] = fmaf(fd[3], cv.w, a3[cc]);
                }
            }
            unsigned long long pbest = ~0ull;
            #pragma unroll
            for (int cc = 0; cc < 8; ++cc) {
                const int kk = lane * 8 + cc;
                float sc = fmaf(-2.0f, (a0[cc] + a1[cc]) + (a2[cc] + a3[cc]), cn[kk]);
                unsigned long long pk = packsi(sc, kk);
                pbest = pk < pbest ? pk : pbest;
            }
            #pragma unroll
            for (int m = 1; m <= 32; m <<= 1) {
                unsigned long long o = __shfl_xor(pbest, m, 64);
                pbest = o < pbest ? o : pbest;
            }
            if (lane == 0) {
                const int bi = (int)(pbest & 0xFFFFFFFFu);
                s_idx[row] = bi;
                out_i[p0 + row] = (float)bi;
            }
        }
    }
    __syncthreads();

    // ---- cooperative coalesced gather of quantized rows (L2-hot cb) ----
    float4* oq = (float4*)out_q;
    const float4* c4g = (const float4*)cb;
    for (int i = tid; i < PTS * 16; i += VQT) {
        const int pt = i >> 4;
        const int q = i & 15;
        oq[(size_t)(p0 + pt) * 16 + q] = c4g[(size_t)s_idx[pt] * 16 + q];
    }
}

extern "C" void kernel_launch(void* const* d_in, const int* in_sizes, int n_in,
                              void* d_out, int out_size, void* d_ws, size_t ws_size,
                              hipStream_t stream) {
    const float* imu = (const float*)d_in[0];
    const float* Wm  = (const float*)d_in[1];
    const float* bm  = (const float*)d_in[2];
    const float* Wp  = (const float*)d_in[3];
    const float* bp  = (const float*)d_in[4];
    const float* cb  = (const float*)d_in[5];

    float* out_q = (float*)d_out;                          // (32,4096,64)
    float* out_i = out_q + (size_t)NB * TN * CDIM;         // (32,4096) as float
    float* out_p = out_i + (size_t)NB * TN;                // (32,4096) phases

    float* cn     = (float*)d_ws;                          // 512 f32
    f16x8* ctiles = (f16x8*)((char*)d_ws + 2048);          // 128 KB code tiles
    f16x8* atiles = (f16x8*)out_q;                         // point tiles in out_q

    prep_kernel<<<545, 256, 0, stream>>>(cb, cn, ctiles, out_p);
    hilbert_phase_kernel<<<NB * NCH / 2, HT, 0, stream>>>(imu, out_p);
    feat_kernel<<<(NB * TN) / 256, 256, 0, stream>>>(imu, Wm, bm, Wp, bp, out_p, atiles);
    vq_kernel<<<(NB * TN) / PTS, VQT, 0, stream>>>(imu, Wm, bm, Wp, bp, cb,
                                                   cn, ctiles, out_p, atiles,
                                                   out_q, out_i);
}

// Round 11
// 171.872 us; speedup vs baseline: 1.0653x; 1.0518x over previous
//
#include <hip/hip_runtime.h>
#include <math.h>

#define TN 4096
#define HN 2048
#define NB 32
#define NCH 9
#define NCODES 512
#define CDIM 64
#define TAU 1e-3f
#define PTS 256          // points per vq block
#define VQT 512          // vq threads per block

typedef _Float16 f16x8 __attribute__((ext_vector_type(8)));
typedef float f32x4 __attribute__((ext_vector_type(4)));

__device__ __forceinline__ float2 cmulf(float2 a, float2 b) {
    return make_float2(a.x * b.x - a.y * b.y, a.x * b.y + a.y * b.x);
}
__device__ __forceinline__ float2 f2add(float2 a, float2 b) {
    return make_float2(a.x + b.x, a.y + b.y);
}
__device__ __forceinline__ float2 f2sub(float2 a, float2 b) {
    return make_float2(a.x - b.x, a.y - b.y);
}

__device__ __forceinline__ unsigned long long packsi(float s, int i) {
    unsigned u = __float_as_uint(s);
    u = (u & 0x80000000u) ? ~u : (u | 0x80000000u);
    return ((unsigned long long)u << 32) | (unsigned)i;
}

// Fragment-tile unit index: [entity16-group][plane][s][hi16][l15], 16B units.
__device__ __forceinline__ size_t aunit(int pbase, int plane, int s, int hi16, int l15) {
    return ((size_t)(((pbase * 2 + plane) * 2 + s) * 4 + hi16) << 4) + l15;
}

// prep: bid<512 zero phases; bid 512..543: code fragment tiles; bid 544: norms.
__global__ __launch_bounds__(256) void prep_kernel(const float* __restrict__ cb,
                                                   float* __restrict__ cn,
                                                   f16x8* __restrict__ ctiles,
                                                   float* __restrict__ ph) {
    const int bid = blockIdx.x;
    const int tid = threadIdx.x;
    if (bid < 512) {
        ph[bid * 256 + tid] = 0.0f;
        return;
    }
    if (bid < 544) {
        const int u = (bid - 512) * 256 + tid;    // 8192 units
        const int l15 = u & 15;
        const int hi16 = (u >> 4) & 3;
        const int s = (u >> 6) & 1;
        const int plane = (u >> 7) & 1;
        const int cbase = u >> 8;
        const int code = cbase * 16 + l15;
        f16x8 out;
        #pragma unroll
        for (int e = 0; e < 8; ++e) {
            float c = cb[code * CDIM + 32 * s + 8 * hi16 + e];
            _Float16 hh = (_Float16)c;
            out[e] = plane ? (_Float16)(c - (float)hh) : hh;
        }
        ctiles[u] = out;
        return;
    }
    for (int k = tid; k < NCODES; k += 256) {
        const float4* c4 = (const float4*)(cb + (size_t)k * CDIM);
        float s = 0.0f;
        #pragma unroll
        for (int q = 0; q < 16; ++q) {
            float4 c = c4[q];
            s = fmaf(c.x, c.x, s);
            s = fmaf(c.y, c.y, s);
            s = fmaf(c.z, c.z, s);
            s = fmaf(c.w, c.w, s);
        }
        cn[k] = s;
    }
}

// Paired-row Hilbert (radix-4 Stockham) — exact r7 form (best measured).
#define HT 512
__global__ __launch_bounds__(HT) void hilbert_phase_kernel(
    const float* __restrict__ x, float* __restrict__ phases) {
    __shared__ float2 bufA[TN];
    __shared__ float2 bufB[TN];
    __shared__ float2 tw[HN];
    const int tid = threadIdx.x;
    const int row1 = 2 * blockIdx.x;
    const int row2 = row1 + 1;
    const int b1 = row1 / NCH;
    const int b2 = row2 / NCH;
    const float* xr1 = x + (size_t)row1 * TN;
    const float* xr2 = x + (size_t)row2 * TN;

    for (int i = tid; i < HN; i += HT) {
        float ang = -3.14159265358979323846f * ((float)i / (float)HN);
        float s, c;
        sincosf(ang, &s, &c);
        tw[i] = make_float2(c, s);
    }
    for (int i = tid; i < TN; i += HT) {
        bufA[i] = make_float2(xr1[i], xr2[i]);
    }
    __syncthreads();

    float2* src = bufA;
    float2* dst = bufB;
    for (int stage = 0; stage < 6; ++stage) {
        const int m = 1 << (2 * stage);
        for (int idx = tid; idx < 1024; idx += HT) {
            const int kk = idx & (m - 1);
            const int jm = idx - kk;
            float2 a0 = src[idx];
            float2 a1 = src[idx + 1024];
            float2 a2 = src[idx + 2048];
            float2 a3 = src[idx + 3072];
            float2 b0 = f2add(a0, a2);
            float2 b1 = f2add(a1, a3);
            float2 b2 = f2sub(a0, a2);
            float2 b3 = f2sub(a1, a3);
            float2 w1 = tw[jm];
            float2 w2 = tw[2 * jm];
            float2 w3 = cmulf(w1, w2);
            float2 y0 = f2add(b0, b1);
            float2 mi = make_float2(b2.x + b3.y, b2.y - b3.x);
            float2 pi_ = make_float2(b2.x - b3.y, b2.y + b3.x);
            dst[4 * jm + kk]         = y0;
            dst[4 * jm + kk + m]     = cmulf(mi, w1);
            dst[4 * jm + kk + 2 * m] = cmulf(f2sub(b0, b1), w2);
            dst[4 * jm + kk + 3 * m] = cmulf(pi_, w3);
        }
        __syncthreads();
        float2* t0 = src; src = dst; dst = t0;
    }
    const float inv = 1.0f / (float)TN;
    for (int i = tid; i < TN; i += HT) {
        float sc;
        if (i == 0 || i == HN) sc = inv;
        else if (i < HN) sc = 2.0f * inv;
        else sc = 0.0f;
        float2 v = src[i];
        v.x *= sc; v.y *= sc;
        src[i] = v;
    }
    __syncthreads();
    for (int stage = 0; stage < 6; ++stage) {
        const int m = 1 << (2 * stage);
        for (int idx = tid; idx < 1024; idx += HT) {
            const int kk = idx & (m - 1);
            const int jm = idx - kk;
            float2 a0 = src[idx];
            float2 a1 = src[idx + 1024];
            float2 a2 = src[idx + 2048];
            float2 a3 = src[idx + 3072];
            float2 b0 = f2add(a0, a2);
            float2 b1 = f2add(a1, a3);
            float2 b2 = f2sub(a0, a2);
            float2 b3 = f2sub(a1, a3);
            float2 w1 = tw[jm];      w1.y = -w1.y;
            float2 w2 = tw[2 * jm];  w2.y = -w2.y;
            float2 w3 = cmulf(w1, w2);
            float2 y0 = f2add(b0, b1);
            float2 pi_ = make_float2(b2.x - b3.y, b2.y + b3.x);
            float2 mi = make_float2(b2.x + b3.y, b2.y - b3.x);
            dst[4 * jm + kk]         = y0;
            dst[4 * jm + kk + m]     = cmulf(pi_, w1);
            dst[4 * jm + kk + 2 * m] = cmulf(f2sub(b0, b1), w2);
            dst[4 * jm + kk + 3 * m] = cmulf(mi, w3);
        }
        __syncthreads();
        float2* t0 = src; src = dst; dst = t0;
    }
    float* ph1 = phases + (size_t)b1 * TN;
    float* ph2 = phases + (size_t)b2 * TN;
    for (int i = tid; i < TN; i += HT) {
        float2 d = src[i];
        float x1v = xr1[i];
        float x2v = xr2[i];
        atomicAdd(&ph1[i], atan2f(d.y - x2v, x1v) * (1.0f / 9.0f));
        atomicAdd(&ph2[i], atan2f(x1v - d.x, x2v) * (1.0f / 9.0f));
    }
}

// feat: writes f16 hi/lo point fragment tiles (aunit layout) into out_q region.
__global__ __launch_bounds__(256) void feat_kernel(
    const float* __restrict__ imu,
    const float* __restrict__ Wm, const float* __restrict__ bm,
    const float* __restrict__ Wp, const float* __restrict__ bp,
    const float* __restrict__ phases,
    f16x8* __restrict__ atiles) {
    const int p = blockIdx.x * 256 + threadIdx.x;
    const int bb = p >> 12;
    const int tt = p & (TN - 1);
    float xc[9];
    #pragma unroll
    for (int c = 0; c < 9; ++c)
        xc[c] = imu[((size_t)(bb * 9 + c)) * TN + tt];
    float sp, cp;
    sincosf(phases[p], &sp, &cp);

    const int pbase = p >> 4;
    const int l15 = p & 15;
    #pragma unroll
    for (int g = 0; g < 8; ++g) {
        float v8[8];
        if (g < 4) {
            #pragma unroll
            for (int e = 0; e < 8; ++e) {
                const int j = 8 * g + e;
                float a = bm[j];
                #pragma unroll
                for (int c = 0; c < 9; ++c) a = fmaf(Wm[j * 9 + c], xc[c], a);
                v8[e] = a;
            }
        } else {
            #pragma unroll
            for (int e = 0; e < 8; ++e) {
                const int j = 8 * (g - 4) + e;
                float a = bp[j];
                #pragma unroll
                for (int c = 0; c < 7; ++c) a = fmaf(Wp[j * 9 + c], xc[c], a);
                a = fmaf(Wp[j * 9 + 7], cp, a);
                a = fmaf(Wp[j * 9 + 8], sp, a);
                v8[e] = a;
            }
        }
        f16x8 hv, lv;
        #pragma unroll
        for (int e = 0; e < 8; ++e) {
            _Float16 hh = (_Float16)v8[e];
            hv[e] = hh;
            lv[e] = (_Float16)(v8[e] - (float)hh);
        }
        const int s = g >> 2;
        const int hi16 = g & 3;
        atiles[aunit(pbase, 0, s, hi16, l15)] = hv;
        atiles[aunit(pbase, 1, s, hi16, l15)] = lv;
    }
}

#define MFMA16(A, B, C) __builtin_amdgcn_mfma_f32_16x16x32_f16((A), (B), (C), 0, 0, 0)

// vq: 512 blocks x 512 thr (8 waves), 256 pts/block. Wave (w,h) owns 32
// codes in regs; points stream from atiles (L2); no k-loop barriers.
// r11 change: u64 pack merge -> f32 (best,sec,idx) top-2 (~3.5x less merge
// VALU, shorter shfl chains), f32 LDS partials (50 KB) -> 2 blocks/CU.
__global__ __launch_bounds__(VQT, 4) void vq_kernel(
    const float* __restrict__ imu,
    const float* __restrict__ Wm, const float* __restrict__ bm,
    const float* __restrict__ Wp, const float* __restrict__ bp,
    const float* __restrict__ cb,
    const float* __restrict__ cn,
    const f16x8* __restrict__ ctiles,
    const float* __restrict__ phases,
    const f16x8* atiles,           // aliases out_q (no __restrict__)
    float* out_q,
    float* __restrict__ out_i) {
    __shared__ float s_b[16][PTS];     // 16 KB  per-(wave,h) best
    __shared__ float s_s[16][PTS];     // 16 KB  per-(wave,h) second
    __shared__ int   s_i[16][PTS];     // 16 KB  per-(wave,h) best idx
    __shared__ int s_idx[PTS];
    __shared__ float s_gap[PTS];
    const int tid = threadIdx.x;
    const int lane = tid & 63;
    const int w = tid >> 6;          // 8 waves
    const int l15 = lane & 15;
    const int hi16 = lane >> 4;
    const int p0 = blockIdx.x * PTS;
    const int pb0 = p0 >> 4;

    for (int h = 0; h < 2; ++h) {
        const int kbase = 64 * w + 32 * h;      // codes [kbase, kbase+32)
        const int cb0 = kbase >> 4;
        // ---- code fragments, loaded once, pinned ----
        f16x8 cH00 = ctiles[aunit(cb0 + 0, 0, 0, hi16, l15)];
        f16x8 cH01 = ctiles[aunit(cb0 + 0, 0, 1, hi16, l15)];
        f16x8 cH10 = ctiles[aunit(cb0 + 1, 0, 0, hi16, l15)];
        f16x8 cH11 = ctiles[aunit(cb0 + 1, 0, 1, hi16, l15)];
        f16x8 cL00 = ctiles[aunit(cb0 + 0, 1, 0, hi16, l15)];
        f16x8 cL01 = ctiles[aunit(cb0 + 0, 1, 1, hi16, l15)];
        f16x8 cL10 = ctiles[aunit(cb0 + 1, 1, 0, hi16, l15)];
        f16x8 cL11 = ctiles[aunit(cb0 + 1, 1, 1, hi16, l15)];
        f32x4 cnv0 = *(const f32x4*)(cn + kbase + 4 * hi16);
        f32x4 cnv1 = *(const f32x4*)(cn + kbase + 16 + 4 * hi16);
        asm volatile("" : "+v"(cH00), "+v"(cH01), "+v"(cH10), "+v"(cH11),
                          "+v"(cL00), "+v"(cL01), "+v"(cL10), "+v"(cL11));
        asm volatile("" : "+v"(cnv0), "+v"(cnv1));

        #pragma unroll 2
        for (int cf = 0; cf < 16; ++cf) {
            const int pbase = pb0 + cf;
            f16x8 bH0 = atiles[aunit(pbase, 0, 0, hi16, l15)];
            f16x8 bH1 = atiles[aunit(pbase, 0, 1, hi16, l15)];
            f16x8 bL0 = atiles[aunit(pbase, 1, 0, hi16, l15)];
            f16x8 bL1 = atiles[aunit(pbase, 1, 1, hi16, l15)];
            f32x4 a0 = (f32x4){0.f, 0.f, 0.f, 0.f};
            f32x4 a1 = (f32x4){0.f, 0.f, 0.f, 0.f};
            a0 = MFMA16(cH00, bH0, a0);
            a0 = MFMA16(cH00, bL0, a0);
            a0 = MFMA16(cL00, bH0, a0);
            a0 = MFMA16(cH01, bH1, a0);
            a0 = MFMA16(cH01, bL1, a0);
            a0 = MFMA16(cL01, bH1, a0);
            a1 = MFMA16(cH10, bH0, a1);
            a1 = MFMA16(cH10, bL0, a1);
            a1 = MFMA16(cL10, bH0, a1);
            a1 = MFMA16(cH11, bH1, a1);
            a1 = MFMA16(cH11, bL1, a1);
            a1 = MFMA16(cL11, bH1, a1);
            // C layout: row (code) = 16rf+4hi16+r, col (point) = 16cf+l15
            // in-lane top-2 of 8 (ascending code order, strict <)
            float b = 3.4e38f, sec = 3.4e38f;
            int bi = 0;
            #pragma unroll
            for (int r = 0; r < 4; ++r) {
                float sc = fmaf(-2.0f, a0[r], cnv0[r]);
                const int ci = kbase + 4 * hi16 + r;
                bool lt = sc < b;
                sec = fminf(sec, lt ? b : sc);
                b = lt ? sc : b;
                bi = lt ? ci : bi;
            }
            #pragma unroll
            for (int r = 0; r < 4; ++r) {
                float sc = fmaf(-2.0f, a1[r], cnv1[r]);
                const int ci = kbase + 16 + 4 * hi16 + r;
                bool lt = sc < b;
                sec = fminf(sec, lt ? b : sc);
                b = lt ? sc : b;
                bi = lt ? ci : bi;
            }
            // cross-hi16 merge (masks 16, 32), tie -> smaller index
            #pragma unroll
            for (int m = 16; m <= 32; m <<= 1) {
                float ob = __shfl_xor(b, m, 64);
                float os = __shfl_xor(sec, m, 64);
                int oi = __shfl_xor(bi, m, 64);
                float mx = fmaxf(b, ob);
                sec = fminf(fminf(sec, os), mx);
                bool take = (ob < b) || (ob == b && oi < bi);
                b = take ? ob : b;
                bi = take ? oi : bi;
            }
            if (hi16 == 0) {
                s_b[2 * w + h][16 * cf + l15] = b;
                s_s[2 * w + h][16 * cf + l15] = sec;
                s_i[2 * w + h][16 * cf + l15] = bi;
            }
        }
    }
    __syncthreads();

    // ---- block merge: 16 partials per point (q ascending = code ranges
    // ascending; tie -> smaller index) ----
    if (tid < PTS) {
        float b = 3.4e38f, sec = 3.4e38f;
        int bi = 0;
        #pragma unroll 4
        for (int q = 0; q < 16; ++q) {
            float ob = s_b[q][tid];
            float os = s_s[q][tid];
            int oi = s_i[q][tid];
            float mx = fmaxf(b, ob);
            sec = fminf(fminf(sec, os), mx);
            bool take = (ob < b) || (ob == b && oi < bi);
            b = take ? ob : b;
            bi = take ? oi : bi;
        }
        s_idx[tid] = bi;
        out_i[p0 + tid] = (float)bi;
        s_gap[tid] = sec - b;
    }
    __syncthreads();

    // ---- rare exact f32 rescan (streaming feature recompute) ----
    {
        bool fl = (lane < 32) && (s_gap[32 * w + (lane & 31)] < TAU);
        unsigned long long bal = __ballot(fl);
        while (bal) {
            const int ln = __builtin_ctzll(bal);
            bal &= bal - 1;
            const int row = 32 * w + ln;
            const int pR = p0 + row;
            const int bbR = pR >> 12;
            const int ttR = pR & (TN - 1);
            float xcR[9];
            #pragma unroll
            for (int c = 0; c < 9; ++c)
                xcR[c] = imu[((size_t)(bbR * 9 + c)) * TN + ttR];
            float spR, cpR;
            sincosf(phases[pR], &spR, &cpR);
            float a0[8], a1[8], a2[8], a3[8];
            #pragma unroll
            for (int cc = 0; cc < 8; ++cc) {
                a0[cc] = 0.f; a1[cc] = 0.f; a2[cc] = 0.f; a3[cc] = 0.f;
            }
            for (int d4 = 0; d4 < 16; ++d4) {
                float fd[4];
                #pragma unroll
                for (int e = 0; e < 4; ++e) {
                    const int j = 4 * d4 + e;
                    float a;
                    if (j < 32) {
                        a = bm[j];
                        #pragma unroll
                        for (int c = 0; c < 9; ++c) a = fmaf(Wm[j * 9 + c], xcR[c], a);
                    } else {
                        const int jj = j - 32;
                        a = bp[jj];
                        #pragma unroll
                        for (int c = 0; c < 7; ++c) a = fmaf(Wp[jj * 9 + c], xcR[c], a);
                        a = fmaf(Wp[jj * 9 + 7], cpR, a);
                        a = fmaf(Wp[jj * 9 + 8], spR, a);
                    }
                    fd[e] = a;
                }
                #pragma unroll
                for (int cc = 0; cc < 8; ++cc) {
                    const float4 cv = ((const float4*)(cb + (size_t)(lane * 8 + cc) * CDIM))[d4];
                    a0[cc] = fmaf(fd[0], cv.x, a0[cc]);
                    a1[cc] = fmaf(fd[1], cv.y, a1[cc]);
                    a2[cc] = fmaf(fd[2], cv.z, a2[cc]);
                    a3[cc] = fmaf(fd[3], cv.w, a3[cc]);
                }
            }
            unsigned long long pbest = ~0ull;
            #pragma unroll
            for (int cc = 0; cc < 8; ++cc) {
                const int kk = lane * 8 + cc;
                float sc = fmaf(-2.0f, (a0[cc] + a1[cc]) + (a2[cc] + a3[cc]), cn[kk]);
                unsigned long long pk = packsi(sc, kk);
                pbest = pk < pbest ? pk : pbest;
            }
            #pragma unroll
            for (int m = 1; m <= 32; m <<= 1) {
                unsigned long long o = __shfl_xor(pbest, m, 64);
                pbest = o < pbest ? o : pbest;
            }
            if (lane == 0) {
                const int bi = (int)(pbest & 0xFFFFFFFFu);
                s_idx[row] = bi;
                out_i[p0 + row] = (float)bi;
            }
        }
    }
    __syncthreads();

    // ---- cooperative coalesced gather of quantized rows (L2-hot cb) ----
    float4* oq = (float4*)out_q;
    const float4* c4g = (const float4*)cb;
    for (int i = tid; i < PTS * 16; i += VQT) {
        const int pt = i >> 4;
        const int q = i & 15;
        oq[(size_t)(p0 + pt) * 16 + q] = c4g[(size_t)s_idx[pt] * 16 + q];
    }
}

extern "C" void kernel_launch(void* const* d_in, const int* in_sizes, int n_in,
                              void* d_out, int out_size, void* d_ws, size_t ws_size,
                              hipStream_t stream) {
    const float* imu = (const float*)d_in[0];
    const float* Wm  = (const float*)d_in[1];
    const float* bm  = (const float*)d_in[2];
    const float* Wp  = (const float*)d_in[3];
    const float* bp  = (const float*)d_in[4];
    const float* cb  = (const float*)d_in[5];

    float* out_q = (float*)d_out;                          // (32,4096,64)
    float* out_i = out_q + (size_t)NB * TN * CDIM;         // (32,4096) as float
    float* out_p = out_i + (size_t)NB * TN;                // (32,4096) phases

    float* cn     = (float*)d_ws;                          // 512 f32
    f16x8* ctiles = (f16x8*)((char*)d_ws + 2048);          // 128 KB code tiles
    f16x8* atiles = (f16x8*)out_q;                         // point tiles in out_q

    prep_kernel<<<545, 256, 0, stream>>>(cb, cn, ctiles, out_p);
    hilbert_phase_kernel<<<NB * NCH / 2, HT, 0, stream>>>(imu, out_p);
    feat_kernel<<<(NB * TN) / 256, 256, 0, stream>>>(imu, Wm, bm, Wp, bp, out_p, atiles);
    vq_kernel<<<(NB * TN) / PTS, VQT, 0, stream>>>(imu, Wm, bm, Wp, bp, cb,
                                                   cn, ctiles, out_p, atiles,
                                                   out_q, out_i);
}